// Round 7
// baseline (277.719 us; speedup 1.0000x reference)
//
#include <hip/hip_runtime.h>
#include <math.h>

// ComplexEMA fused single-kernel.
//   y[b,d,t] = Re(sum_n gam_dn * h_dn[t]) + omega_d * x[b,d,t],
//   h[t] = q*h[t-1] + p*x[t].   u = h/p (p folded into gam / final write).
// Conjugate-form state (v = -imag) -> no component swaps.
//
// One wave = one row (b,d). lane = chunk (64 chunks x 64 steps).
//   A) local 64-step recurrence from zero (x direct from global, 64B bursts)
//   B) Kogge-Stone scan over chunks via __shfl_up on affine maps (A=q^64),
//      processed in 4 mode-groups of 4 (#pragma unroll 1) to cap the
//      shfl-temp register peak (R6: compiler clamped to 76 VGPR + spilled).
//   C) rerun from correct chunk inits, y overwrites the x register buffer.
// Wave-uniform coefficients (q, g, omega) pinned to SGPRs via readfirstlane.
// __launch_bounds__(256,3): grid is 4096 waves = 4/SIMD cap, so allow ~170
// VGPRs instead of spilling for unreachable occupancy (R5/R6 lesson:
// spill scratch traffic cost 190-1200 MB of HBM writes).

constexpr int kD = 2048, kN = 16, kB = 2, kL = 4096;
constexpr int kRows = kB * kD;      // 4096 rows = 4096 waves
constexpr float kSCALE = 0.25f;     // sqrt(1/N)

static __device__ __forceinline__ float uniformf(float v) {
  // wave-uniform value -> SGPR
  return __int_as_float(__builtin_amdgcn_readfirstlane(__float_as_int(v)));
}

static __device__ __forceinline__ void load16(const float* __restrict__ p, float* v) {
  const float4* p4 = (const float4*)p;
  float4 t0 = p4[0], t1 = p4[1], t2 = p4[2], t3 = p4[3];
  v[0]=t0.x; v[1]=t0.y; v[2]=t0.z; v[3]=t0.w;
  v[4]=t1.x; v[5]=t1.y; v[6]=t1.z; v[7]=t1.w;
  v[8]=t2.x; v[9]=t2.y; v[10]=t2.z; v[11]=t2.w;
  v[12]=t3.x; v[13]=t3.y; v[14]=t3.z; v[15]=t3.w;
}

static __device__ __forceinline__ void store16(float* __restrict__ p, const float* v) {
  float4* p4 = (float4*)p;
  p4[0] = make_float4(v[0], v[1], v[2], v[3]);
  p4[1] = make_float4(v[4], v[5], v[6], v[7]);
  p4[2] = make_float4(v[8], v[9], v[10], v[11]);
  p4[3] = make_float4(v[12], v[13], v[14], v[15]);
}

// 16 recurrence steps, no output (pass A)
static __device__ __forceinline__ void steps16A(const float* xv, float* ur, float* uv,
                                                const float* qr, const float* qv) {
#pragma unroll
  for (int j = 0; j < 16; j++) {
    float xj = xv[j];
#pragma unroll
    for (int m = 0; m < 16; m++) {
      float nr = fmaf(qr[m], ur[m], fmaf(-qv[m], uv[m], xj));
      uv[m] = fmaf(qr[m], uv[m], qv[m] * ur[m]);
      ur[m] = nr;
    }
  }
}

// 16 recurrence steps + y emission, y overwrites v[] in place (pass C)
static __device__ __forceinline__ void steps16C(float* v, float* ur, float* uv,
    const float* qr, const float* qv, const float* gr, const float* gv, float om) {
#pragma unroll
  for (int j = 0; j < 16; j++) {
    float xj = v[j];
    float a[4] = {0.f, 0.f, 0.f, 0.f};
#pragma unroll
    for (int m = 0; m < 16; m++) {
      float nr = fmaf(qr[m], ur[m], fmaf(-qv[m], uv[m], xj));
      float nv = fmaf(qr[m], uv[m], qv[m] * ur[m]);
      ur[m] = nr; uv[m] = nv;
      a[m & 3] = fmaf(gr[m], nr, fmaf(gv[m], nv, a[m & 3]));
    }
    v[j] = fmaf(om, xj, (a[0] + a[1]) + (a[2] + a[3]));
  }
}

__global__ __launch_bounds__(256, 3) void ema_kernel(
    const float* __restrict__ x, const float* __restrict__ alpha,
    const float* __restrict__ delta, const float* __restrict__ theta,
    const float* __restrict__ gamma, const float* __restrict__ omega,
    float* __restrict__ y, float* __restrict__ hout) {
  __shared__ float coeff[4][96];  // per wave/row: [0)qr [16)qv [32)gr [48)gv [64)p [80]om

  const int tid = threadIdx.x, wave = tid >> 6, lane = tid & 63;
  const int row = blockIdx.x * 4 + wave, d = row & (kD - 1);

  // ---- coefficients (lanes 0..15 of each wave -> LDS) ----
  if (lane < kN) {
    int n = lane, i = d * kN + n;
    float p  = 1.f / (1.f + expf(-alpha[i]));
    float dd = 1.f / (1.f + expf(-delta[i]));
    float th = 1.f / (1.f + expf(-theta[d]));
    float phi = (float)(n + 1) * th * 0.39269908169872414f;  // 2*pi/16
    float r = 1.f - p * dd;
    float s, c;
    sincosf(phi, &s, &c);
    coeff[wave][n]      = r * c;                         // qr
    coeff[wave][16 + n] = -r * s;                        // qv = -qi
    coeff[wave][32 + n] = p * kSCALE * gamma[2 * i];     // gr
    coeff[wave][48 + n] = p * kSCALE * gamma[2 * i + 1]; // gv
    coeff[wave][64 + n] = p;
    if (n == 0) coeff[wave][80] = omega[d];
  }
  __syncthreads();

  // ---- q into SGPRs ----
  float qr[16], qv[16];
#pragma unroll
  for (int m = 0; m < 16; m++) {
    qr[m] = uniformf(coeff[wave][m]);
    qv[m] = uniformf(coeff[wave][16 + m]);
  }

  const float* xrow = x + (size_t)row * kL + lane * 64;

  // ---- pass A: local recurrence from zero ----
  float ur[16], uv[16];
#pragma unroll
  for (int m = 0; m < 16; m++) { ur[m] = 0.f; uv[m] = 0.f; }
  float xa[16], xb[16];
  load16(xrow, xa);
  load16(xrow + 16, xb);          // prefetch
  steps16A(xa, ur, uv, qr, qv);
  load16(xrow + 32, xa);          // prefetch
  steps16A(xb, ur, uv, qr, qv);
  load16(xrow + 48, xb);          // prefetch
  steps16A(xa, ur, uv, qr, qv);
  steps16A(xb, ur, uv, qr, qv);

  // ---- scan over chunks: affine (A,B), A = q^64; 4 mode-groups of 4 ----
#pragma unroll 1
  for (int g4 = 0; g4 < 4; g4++) {
    float Ar[4], Av[4];
#pragma unroll
    for (int m = 0; m < 4; m++) { Ar[m] = qr[4 * g4 + m]; Av[m] = qv[4 * g4 + m]; }
#pragma unroll
    for (int k = 0; k < 6; k++) {   // 6 squarings -> q^64
#pragma unroll
      for (int m = 0; m < 4; m++) {
        float t = Ar[m] * Ar[m] - Av[m] * Av[m];
        Av[m] = 2.f * Ar[m] * Av[m];
        Ar[m] = t;
      }
    }
#pragma unroll
    for (int dd2 = 1; dd2 <= 32; dd2 <<= 1) {   // Kogge-Stone inclusive
#pragma unroll
      for (int m = 0; m < 4; m++) {
        int mm = 4 * g4 + m;
        float oBr = __shfl_up(ur[mm], dd2, 64);
        float oBv = __shfl_up(uv[mm], dd2, 64);
        float oAr = __shfl_up(Ar[m], dd2, 64);
        float oAv = __shfl_up(Av[m], dd2, 64);
        if (lane >= dd2) {
          ur[mm] = fmaf(Ar[m], oBr, fmaf(-Av[m], oBv, ur[mm]));
          uv[mm] = fmaf(Ar[m], oBv, fmaf(Av[m], oBr, uv[mm]));
          float t = Ar[m] * oAr - Av[m] * oAv;
          Av[m] = fmaf(Ar[m], oAv, Av[m] * oAr);
          Ar[m] = t;
        }
      }
    }
  }

  // ---- h_last: lane 63 holds the row's final state. h = p*u, imag = -uv ----
  if (lane == 63) {
    float4* hp = (float4*)(hout + (size_t)row * 32);
#pragma unroll
    for (int k = 0; k < 8; k++) {
      int m0 = 2 * k, m1 = 2 * k + 1;
      float p0 = coeff[wave][64 + m0];
      float p1 = coeff[wave][64 + m1];
      hp[k] = make_float4(p0 * ur[m0], -p0 * uv[m0], p1 * ur[m1], -p1 * uv[m1]);
    }
  }

  // ---- exclusive shift: state entering my chunk = inclusive[lane-1] ----
#pragma unroll
  for (int m = 0; m < 16; m++) {
    float hr = __shfl_up(ur[m], 1, 64);
    float hv = __shfl_up(uv[m], 1, 64);
    ur[m] = (lane == 0) ? 0.f : hr;
    uv[m] = (lane == 0) ? 0.f : hv;
  }

  // ---- g, omega into SGPRs ----
  float gr[16], gv[16];
#pragma unroll
  for (int m = 0; m < 16; m++) {
    gr[m] = uniformf(coeff[wave][32 + m]);
    gv[m] = uniformf(coeff[wave][48 + m]);
  }
  float om = uniformf(coeff[wave][80]);

  // ---- pass C: recurrence from correct inits, emit y ----
  float* yrow = y + (size_t)row * kL + lane * 64;
  load16(xrow, xa);               // L2/L3-warm re-read
  load16(xrow + 16, xb);
  steps16C(xa, ur, uv, qr, qv, gr, gv, om);
  store16(yrow, xa);
  load16(xrow + 32, xa);
  steps16C(xb, ur, uv, qr, qv, gr, gv, om);
  store16(yrow + 16, xb);
  load16(xrow + 48, xb);
  steps16C(xa, ur, uv, qr, qv, gr, gv, om);
  store16(yrow + 32, xa);
  steps16C(xb, ur, uv, qr, qv, gr, gv, om);
  store16(yrow + 48, xb);
}

extern "C" void kernel_launch(void* const* d_in, const int* in_sizes, int n_in,
                              void* d_out, int out_size, void* d_ws, size_t ws_size,
                              hipStream_t stream) {
  const float* x     = (const float*)d_in[0];
  const float* alpha = (const float*)d_in[1];
  const float* delta = (const float*)d_in[2];
  const float* theta = (const float*)d_in[3];
  const float* gamma = (const float*)d_in[4];
  const float* omega = (const float*)d_in[5];
  float* y    = (float*)d_out;
  float* hout = y + (size_t)kB * kD * kL;   // (B,D,N,2) after y
  ema_kernel<<<kRows / 4, 256, 0, stream>>>(x, alpha, delta, theta, gamma,
                                            omega, y, hout);
}